// Round 1
// baseline (225.239 us; speedup 1.0000x reference)
//
#include <hip/hip_runtime.h>

#define NN 400
#define HID 96
#define EDGES 79800
#define BATCH 16
#define ROWS (BATCH*EDGES)
#define NTILES 4988
#define NBLK 512

typedef _Float16 f16;
typedef f16 f16x8 __attribute__((ext_vector_type(8)));
typedef float f32x16 __attribute__((ext_vector_type(16)));
typedef unsigned int u32;

union H8 { f16x8 h; u32 u[4]; };

__device__ inline f16x8 habs8(f16x8 x) {
  H8 t; t.h = x;
  t.u[0] &= 0x7fff7fffu; t.u[1] &= 0x7fff7fffu;
  t.u[2] &= 0x7fff7fffu; t.u[3] &= 0x7fff7fffu;
  return t.h;
}

// ---------------- prep: zero mean accum + swizzle W_d1/W_d2 into B-fragment order ---------------
// wfr dword D = ((kstep*2+q)*64 + lane)*4 + dj ; layer2 starts at dword 9216.
// frag element j of lane(c,h2): B[k=16t+8*h2+j][d=2c+q]
__global__ void prep_kernel(const float* __restrict__ W1, const float* __restrict__ W2,
                            u32* __restrict__ wfr, float* __restrict__ msum) {
  int D = blockIdx.x*256 + threadIdx.x;
  if (blockIdx.x == 0 && threadIdx.x < 16) msum[threadIdx.x] = 0.f;
  if (D >= 11264) return;
  const float* W = W1;
  int Dl = D;
  if (D >= 9216) { W = W2; Dl = D - 9216; }
  int tq = Dl >> 8;
  int t = tq >> 1, q = tq & 1;
  int rem = Dl & 255;
  int L = rem >> 2, dj = rem & 3;
  int c = L & 31, h2 = L >> 5;
  int k = 16*t + 8*h2 + 2*dj;
  int d = 2*c + q;
  f16 lo = (f16)W[k*64 + d];
  f16 hi = (f16)W[(k+1)*64 + d];
  union { f16 h[2]; u32 u; } cv;
  cv.h[0] = lo; cv.h[1] = hi;
  wfr[D] = cv.u;
}

// ---------------- per-batch mean of sc_matrix (atomic accumulate) ----------------
__global__ void mean_kernel(const float* __restrict__ sc, float* __restrict__ msum) {
  int b = blockIdx.x >> 2, part = blockIdx.x & 3;
  const float4* p = (const float4*)(sc + (size_t)b*160000) + part*10000;
  float s = 0.f;
  for (int i = threadIdx.x; i < 10000; i += 256) {
    float4 v = p[i];
    s += (v.x + v.y) + (v.z + v.w);
  }
  __shared__ float red[256];
  red[threadIdx.x] = s; __syncthreads();
  for (int off = 128; off > 0; off >>= 1) {
    if (threadIdx.x < off) red[threadIdx.x] += red[threadIdx.x + off];
    __syncthreads();
  }
  if (threadIdx.x == 0) atomicAdd(&msum[b], red[0]);
}

// ---------------- encoder: feats -> h (f32 vector math, h stored f16) ----------------
__global__ __launch_bounds__(128) void encoder_kernel(
    const float* __restrict__ nf, const float* __restrict__ sc,
    const float* __restrict__ smean, const float* __restrict__ sstd,
    const float* __restrict__ We1, const float* __restrict__ be1, const float* __restrict__ ae1,
    const float* __restrict__ We2, const float* __restrict__ be2, const float* __restrict__ ae2,
    const float* __restrict__ msum, f16* __restrict__ hout) {
  __shared__ float feats[8][408];
  __shared__ float h1[8][96];
  int b = blockIdx.x / 50, ng = blockIdx.x % 50;
  int n0 = ng*8;
  int tid = threadIdx.x;
  float rm = msum[b] * (1.f/160000.f);
  rm = 1.f / fmaxf(rm, 1e-8f);
  if (tid < 64) {
    int n = tid >> 3, f = tid & 7;
    feats[n][f] = (nf[((b*NN) + n0 + n)*8 + f] - smean[f]) / (sstd[f] + 1e-8f);
  }
  for (int idx = tid; idx < 8*NN; idx += 128) {
    int n = idx / NN, k2 = idx - n*NN;
    feats[n][8+k2] = sc[((size_t)b*NN + n0 + n)*NN + k2] * rm;
  }
  __syncthreads();
  float a1 = *ae1, a2 = *ae2;
  if (tid < 96) {
    float acc[8];
    float bv = be1[tid];
#pragma unroll
    for (int n = 0; n < 8; ++n) acc[n] = bv;
    for (int k = 0; k < 408; k += 4) {
      float w0 = We1[(k+0)*96 + tid], w1 = We1[(k+1)*96 + tid];
      float w2 = We1[(k+2)*96 + tid], w3 = We1[(k+3)*96 + tid];
#pragma unroll
      for (int n = 0; n < 8; ++n) {
        float4 f4 = *(const float4*)&feats[n][k];
        acc[n] += f4.x*w0 + f4.y*w1 + f4.z*w2 + f4.w*w3;
      }
    }
#pragma unroll
    for (int n = 0; n < 8; ++n) h1[n][tid] = fmaxf(acc[n], a1*acc[n]);
  }
  __syncthreads();
  if (tid < 96) {
    float acc[8];
    float bv = be2[tid];
#pragma unroll
    for (int n = 0; n < 8; ++n) acc[n] = bv;
    for (int k = 0; k < 96; k += 4) {
      float w0 = We2[(k+0)*96 + tid], w1 = We2[(k+1)*96 + tid];
      float w2 = We2[(k+2)*96 + tid], w3 = We2[(k+3)*96 + tid];
#pragma unroll
      for (int n = 0; n < 8; ++n) {
        float4 f4 = *(const float4*)&h1[n][k];
        acc[n] += f4.x*w0 + f4.y*w1 + f4.z*w2 + f4.w*w3;
      }
    }
#pragma unroll
    for (int n = 0; n < 8; ++n) {
      float v = acc[n]; v = fmaxf(v, a2*v);
      hout[((b*NN) + n0 + n)*HID + tid] = (f16)v;
    }
  }
}

// ---------------- decoder: per-edge 3-layer MLP via f16 MFMA ----------------
// A = edge features built JIT (sum|absdiff|prod of gathered h rows), B = pre-swizzled weights.
// n-tile q maps to logical dim d=2c+q so z1/z2 pack into f16 pairs (pkrtz) for LDS round-trips.
__global__ __launch_bounds__(256, 2) void decoder_kernel(
    const f16* __restrict__ hbuf, const float* __restrict__ wsfr,
    const float* __restrict__ b1, const float* __restrict__ b2,
    const float* __restrict__ ad1, const float* __restrict__ ad2,
    const float* __restrict__ W3, const float* __restrict__ b3p,
    const int* __restrict__ ei, const int* __restrict__ ej,
    float* __restrict__ out) {
  __shared__ f16 wfr[22528];          // 45056 B: 18 ksteps L1 + 4 ksteps L2, frag order
  __shared__ u32 zbuf[4][1152];       // per-wave z buffer (z1: [row][36], z2: [row][33])
  {
    float4* dst = (float4*)wfr;
    const float4* src = (const float4*)wsfr;
    for (int i = threadIdx.x; i < 2816; i += 256) dst[i] = src[i];
  }
  __syncthreads();
  const int lane = threadIdx.x & 63;
  const int wid  = threadIdx.x >> 6;
  const int c = lane & 31, h2 = lane >> 5;
  u32* zb = zbuf[wid];
  const float2 b1v = *(const float2*)(b1 + 2*c);
  const float2 b2v = *(const float2*)(b2 + 2*c);
  const float2 w3v = *(const float2*)(W3 + 2*c);
  const float a1 = *ad1, a2 = *ad2, b3 = *b3p;
  const f16* wfr2 = wfr + 18432;

  for (int tile = blockIdx.x; tile < NTILES; tile += NBLK) {
    const int rbase = tile*256 + wid*64;
    const f16* pi[2]; const f16* pj[2];
    bool valid[2];
#pragma unroll
    for (int m = 0; m < 2; ++m) {
      int r = rbase + 32*m + c;
      valid[m] = (r < ROWS);
      unsigned rr = valid[m] ? (unsigned)r : (unsigned)(ROWS-1);
      unsigned bb = rr / (unsigned)EDGES;
      int e = (int)(rr - bb*(unsigned)EDGES);
      int ii = ei[e], jj = ej[e];
      pi[m] = hbuf + (((int)bb*NN + ii)*HID + 8*h2);
      pj[m] = hbuf + (((int)bb*NN + jj)*HID + 8*h2);
    }
    f32x16 acc[2][2];
#pragma unroll
    for (int r = 0; r < 16; ++r) {
      acc[0][0][r] = b1v.x; acc[0][1][r] = b1v.y;
      acc[1][0][r] = b1v.x; acc[1][1][r] = b1v.y;
    }
    // layer 1: K=288 in 6 octet steps x {sum,absdiff,prod}
#pragma unroll
    for (int t = 0; t < 6; ++t) {
      f16x8 bs0 = *(const f16x8*)(wfr + (((t   )*2+0)*64 + lane)*8);
      f16x8 bs1 = *(const f16x8*)(wfr + (((t   )*2+1)*64 + lane)*8);
      f16x8 bd0 = *(const f16x8*)(wfr + (((t+ 6)*2+0)*64 + lane)*8);
      f16x8 bd1 = *(const f16x8*)(wfr + (((t+ 6)*2+1)*64 + lane)*8);
      f16x8 bp0 = *(const f16x8*)(wfr + (((t+12)*2+0)*64 + lane)*8);
      f16x8 bp1 = *(const f16x8*)(wfr + (((t+12)*2+1)*64 + lane)*8);
#pragma unroll
      for (int m = 0; m < 2; ++m) {
        f16x8 hi = *(const f16x8*)(pi[m] + 16*t);
        f16x8 hj = *(const f16x8*)(pj[m] + 16*t);
        f16x8 su = hi + hj;
        f16x8 di = habs8(hi - hj);
        f16x8 pr = hi * hj;
        acc[m][0] = __builtin_amdgcn_mfma_f32_32x32x16_f16(su, bs0, acc[m][0], 0,0,0);
        acc[m][1] = __builtin_amdgcn_mfma_f32_32x32x16_f16(su, bs1, acc[m][1], 0,0,0);
        acc[m][0] = __builtin_amdgcn_mfma_f32_32x32x16_f16(di, bd0, acc[m][0], 0,0,0);
        acc[m][1] = __builtin_amdgcn_mfma_f32_32x32x16_f16(di, bd1, acc[m][1], 0,0,0);
        acc[m][0] = __builtin_amdgcn_mfma_f32_32x32x16_f16(pr, bp0, acc[m][0], 0,0,0);
        acc[m][1] = __builtin_amdgcn_mfma_f32_32x32x16_f16(pr, bp1, acc[m][1], 0,0,0);
      }
    }
    // layer-2 weight frags (held in regs across both m-subtiles)
    f16x8 w2f[4][2];
#pragma unroll
    for (int t2 = 0; t2 < 4; ++t2) {
      w2f[t2][0] = *(const f16x8*)(wfr2 + ((t2*2+0)*64 + lane)*8);
      w2f[t2][1] = *(const f16x8*)(wfr2 + ((t2*2+1)*64 + lane)*8);
    }
#pragma unroll
    for (int m = 0; m < 2; ++m) {
      // prelu(z1) -> pack pairs (dims 2c,2c+1) -> LDS [row][pair c], stride 36 dwords
#pragma unroll
      for (int r = 0; r < 16; ++r) {
        float x0 = acc[m][0][r]; x0 = fmaxf(x0, a1*x0);
        float x1 = acc[m][1][r]; x1 = fmaxf(x1, a1*x1);
        auto pk = __builtin_amdgcn_cvt_pkrtz(x0, x1);
        union { decltype(pk) h; u32 u; } cv; cv.h = pk;
        int row = (r & 3) + 8*(r >> 2) + 4*h2;
        zb[row*36 + c] = cv.u;
      }
      // read back as layer-2 A-frags: edge=c, dims 16t2+8h2..+8 (aligned b128)
      f16x8 za[4];
#pragma unroll
      for (int t2 = 0; t2 < 4; ++t2)
        za[t2] = *(const f16x8*)((const f16*)zb + (c*36 + 8*t2 + 4*h2)*2);
      f32x16 zacc[2];
#pragma unroll
      for (int r = 0; r < 16; ++r) { zacc[0][r] = b2v.x; zacc[1][r] = b2v.y; }
#pragma unroll
      for (int t2 = 0; t2 < 4; ++t2) {
        zacc[0] = __builtin_amdgcn_mfma_f32_32x32x16_f16(za[t2], w2f[t2][0], zacc[0], 0,0,0);
        zacc[1] = __builtin_amdgcn_mfma_f32_32x32x16_f16(za[t2], w2f[t2][1], zacc[1], 0,0,0);
      }
      // prelu(z2) * W3 -> pack -> LDS [row][33]; then per-edge sum (lane pair c / c+32)
#pragma unroll
      for (int r = 0; r < 16; ++r) {
        float x0 = zacc[0][r]; x0 = fmaxf(x0, a2*x0); x0 *= w3v.x;
        float x1 = zacc[1][r]; x1 = fmaxf(x1, a2*x1); x1 *= w3v.y;
        auto pk = __builtin_amdgcn_cvt_pkrtz(x0, x1);
        union { decltype(pk) h; u32 u; } cv; cv.h = pk;
        int row = (r & 3) + 8*(r >> 2) + 4*h2;
        zb[row*33 + c] = cv.u;
      }
      float ssum = 0.f;
#pragma unroll
      for (int s2 = 0; s2 < 16; ++s2) {
        union { u32 u; f16 h[2]; } cv;
        cv.u = zb[c*33 + 16*h2 + s2];
        ssum += (float)cv.h[0] + (float)cv.h[1];
      }
      ssum += __shfl_xor(ssum, 32);
      if (h2 == 0 && valid[m]) out[rbase + 32*m + c] = ssum + b3;
    }
  }
}

extern "C" void kernel_launch(void* const* d_in, const int* in_sizes, int n_in,
                              void* d_out, int out_size, void* d_ws, size_t ws_size,
                              hipStream_t stream) {
  const float* nf  = (const float*)d_in[1];
  const float* sc  = (const float*)d_in[2];
  const float* sm  = (const float*)d_in[3];
  const float* ss  = (const float*)d_in[4];
  const float* We1 = (const float*)d_in[5];
  const float* be1 = (const float*)d_in[6];
  const float* ae1 = (const float*)d_in[7];
  const float* We2 = (const float*)d_in[8];
  const float* be2 = (const float*)d_in[9];
  const float* ae2 = (const float*)d_in[10];
  const float* W1  = (const float*)d_in[11];
  const float* b1  = (const float*)d_in[12];
  const float* a1  = (const float*)d_in[13];
  const float* W2  = (const float*)d_in[14];
  const float* b2  = (const float*)d_in[15];
  const float* a2  = (const float*)d_in[16];
  const float* W3  = (const float*)d_in[17];
  const float* b3  = (const float*)d_in[18];
  const int*   ei  = (const int*)d_in[19];
  const int*   ej  = (const int*)d_in[20];
  float* out = (float*)d_out;

  char* ws = (char*)d_ws;
  float* msum = (float*)ws;                         // 16 f32 (zeroed by prep block 0)
  f16*   hbuf = (f16*)(ws + 64);                    // 614400 f16 = 1228800 B
  u32*   wfr  = (u32*)(ws + 64 + 1228800);          // 11264 dwords = 45056 B

  prep_kernel<<<44, 256, 0, stream>>>(W1, W2, wfr, msum);
  mean_kernel<<<64, 256, 0, stream>>>(sc, msum);
  encoder_kernel<<<800, 128, 0, stream>>>(nf, sc, sm, ss, We1, be1, ae1,
                                          We2, be2, ae2, msum, hbuf);
  decoder_kernel<<<NBLK, 256, 0, stream>>>(hbuf, (const float*)wfr, b1, b2,
                                           a1, a2, W3, b3, ei, ej, out);
}